// Round 1
// baseline (1216.837 us; speedup 1.0000x reference)
//
#include <hip/hip_runtime.h>
#include <math.h>

// ---------------------------------------------------------------------------
// VQVAEZMultiScale round 1 — correctness-first.
//   S=3 scales, C=256 channels, K=512 codes, B=8, base grid 64x64.
//   Unique feature rows: scale0 32768, scale1 8192, scale2 2048 -> 43008.
//   Distances in fp64 (exact from fp32 inputs) to make argmin robust vs np ref.
// Workspace layout (float units):
//   feat   [43008][256]        @ 0
//   prob1  [43008]             @ 11010048
//   idx1   [43008] (int)       @ 11053056
//   idx2   [32768] (int)       @ 11096064
//   img1   [8][3][128][128]    @ 11128832
//   img2   [8][3][64][64]      @ 11522048
//   enormd [43008] (double)    @ 11620352  (86016 float slots)
//   cnormd [1024]  (double)    @ 11706368  (2048 float slots)
//   total 11708416 floats = 46.8 MB
// Output layout (float, concatenated):
//   out0 encodes[0] NCHW [8][256][64][64]  @ 0
//   out1 zidx NCHW [8][2][64][64] (as float) @ 8388608
//   out2 ste0 NCHW [8][256][64][64] @ 8454144
// ---------------------------------------------------------------------------

#define FEAT_OFF   0
#define PROB_OFF   11010048
#define IDX1_OFF   11053056
#define IDX2_OFF   11096064
#define IMG1_OFF   11128832
#define IMG2_OFF   11522048
#define ENORM_OFF  11620352
#define CNORM_OFF  11706368

// ---- bilinear downsample: out[b,ci,y,x] = ((p(fy+o,fx+o)+p(fy+o+1,fx+o))*0.5
//                                           +(p(fy+o,fx+o+1)+p(fy+o+1,fx+o+1))*0.5)*0.5
__global__ void ds_kernel(const float* __restrict__ img, float* __restrict__ out,
                          int Hout, int Wout, int o, int f) {
    int i = blockIdx.x * blockDim.x + threadIdx.x;
    int total = 8 * 3 * Hout * Wout;
    if (i >= total) return;
    int x = i % Wout;
    int t = i / Wout;
    int y = t % Hout;
    int bc = t / Hout;                       // b*3 + ci
    const float* base = img + ((size_t)bc * 256 + (size_t)(y * f + o)) * 256;
    int cx = x * f + o;
    float v00 = base[cx],       v10 = base[256 + cx];
    float v01 = base[cx + 1],   v11 = base[256 + cx + 1];
    // reference order: H-average first, then W-average
    out[i] = ((v00 + v10) * 0.5f + (v01 + v11) * 0.5f) * 0.5f;
}

// ---- per-code squared norms (fp64), both codebooks (rows 0..511 cb0, 512..1023 cb1)
__global__ void cnorm_kernel(const float* __restrict__ cb, double* __restrict__ cnormd) {
    int row = blockIdx.x;                    // 0..1023
    const float* p = cb + (size_t)row * 256;
    int lane = threadIdx.x;                  // 64 threads
    double s = 0.0;
    for (int c = lane; c < 256; c += 64) {
        double v = (double)p[c];
        s = fma(v, v, s);
    }
    #pragma unroll
    for (int off = 32; off; off >>= 1) s += __shfl_down(s, off);
    if (lane == 0) cnormd[row] = s;
}

// ---- stride-4 patchify conv, one block per (b, y-row). threads = channels.
//      Writes feat NHWC-ish [row][256] and enormd (fp64 ||e||^2).
__launch_bounds__(256)
__global__ void encode_kernel(const float* __restrict__ img,
                              const float* __restrict__ w,
                              const float* __restrict__ bias,
                              float* __restrict__ feat,
                              double* __restrict__ enormd,
                              int Hout, int Wout, int rowbase) {
    __shared__ float patch[12 * 256];        // 3 ci * 4 kh rows of Wimg floats
    __shared__ double wsumd[64][4];
    int tid = threadIdx.x;
    int b = blockIdx.x / Hout, y = blockIdx.x % Hout;
    int Himg = Hout * 4, Wimg = Wout * 4;

    // stage the 12 image rows this output row needs (coalesced)
    const float* ibase = img + (size_t)b * 3 * Himg * Wimg;
    int nload = 12 * Wimg;
    for (int i = tid; i < nload; i += 256) {
        int col = i % Wimg, r = i / Wimg;    // r = ci*4 + kh
        int ci = r >> 2, kh = r & 3;
        patch[r * Wimg + col] = ibase[((size_t)ci * Himg + 4 * y + kh) * Wimg + col];
    }
    // per-thread weights: channel = tid
    float wr[48];
    #pragma unroll
    for (int j = 0; j < 48; j++) wr[j] = w[tid * 48 + j];
    float bv = bias[tid];
    __syncthreads();

    int rb = rowbase + (b * Hout + y) * Wout;
    for (int x = 0; x < Wout; x++) {
        float acc = 0.f;
        #pragma unroll
        for (int ci = 0; ci < 3; ci++)
            #pragma unroll
            for (int kh = 0; kh < 4; kh++) {
                const float* pr = &patch[(ci * 4 + kh) * Wimg + 4 * x];
                #pragma unroll
                for (int kw = 0; kw < 4; kw++)
                    acc = fmaf(pr[kw], wr[ci * 16 + kh * 4 + kw], acc);
            }
        acc += bv;
        feat[(size_t)(rb + x) * 256 + tid] = acc;   // coalesced: lanes = channels
        // fp64 ||e||^2 block-reduction (wave butterfly + 4 partials)
        double sq = (double)acc * (double)acc;
        #pragma unroll
        for (int off = 32; off; off >>= 1) sq += __shfl_xor(sq, off);
        if ((tid & 63) == 0) wsumd[x][tid >> 6] = sq;
    }
    __syncthreads();
    if (tid < Wout)
        enormd[rb + tid] = wsumd[tid][0] + wsumd[tid][1] + wsumd[tid][2] + wsumd[tid][3];
}

// ---- distance match: 16 rows/block vs all 512 codes, K=256, fp64 accumulate.
//      d = (||e||^2 - 2*dot) + ||c||^2 ; argmin with first-min tie rule;
//      maxprob = exp(-log(sum exp(dmin - d))).
template <bool WANT_PROB>
__launch_bounds__(256)
__global__ void match_kernel(const float* __restrict__ feat,
                             const double* __restrict__ enormd,
                             const float* __restrict__ cb,
                             const double* __restrict__ cnormd,
                             float* __restrict__ prob,
                             int* __restrict__ idx) {
    __shared__ float et[16][17];             // +1 pad: conflict-free
    __shared__ float ct[512][17];
    int tid = threadIdx.x;
    int row0 = blockIdx.x * 16;
    int ty = tid >> 5, tx = tid & 31;        // 8 row-groups x 32 code-lanes
    double acc[2][16];
    #pragma unroll
    for (int r = 0; r < 2; r++)
        #pragma unroll
        for (int q = 0; q < 16; q++) acc[r][q] = 0.0;

    for (int c0 = 0; c0 < 256; c0 += 16) {
        if (tid < 64) {                      // 16 rows x 16 ch = 64 float4
            int r = tid >> 2, f = tid & 3;
            float4 v = *(const float4*)(feat + (size_t)(row0 + r) * 256 + c0 + f * 4);
            et[r][f * 4 + 0] = v.x; et[r][f * 4 + 1] = v.y;
            et[r][f * 4 + 2] = v.z; et[r][f * 4 + 3] = v.w;
        }
        #pragma unroll
        for (int i = 0; i < 8; i++) {        // 512 codes x 16 ch = 2048 float4
            int id = i * 256 + tid;
            int k = id >> 2, f = id & 3;
            float4 v = *(const float4*)(cb + (size_t)k * 256 + c0 + f * 4);
            ct[k][f * 4 + 0] = v.x; ct[k][f * 4 + 1] = v.y;
            ct[k][f * 4 + 2] = v.z; ct[k][f * 4 + 3] = v.w;
        }
        __syncthreads();
        for (int kc = 0; kc < 16; kc++) {
            double e0 = (double)et[ty * 2 + 0][kc];   // broadcast reads
            double e1 = (double)et[ty * 2 + 1][kc];
            #pragma unroll
            for (int q = 0; q < 16; q++) {
                double cv = (double)ct[q * 32 + tx][kc];  // banks (17*tx+kc)%32 distinct
                acc[0][q] = fma(e0, cv, acc[0][q]);
                acc[1][q] = fma(e1, cv, acc[1][q]);
            }
        }
        __syncthreads();
    }

    #pragma unroll
    for (int rr = 0; rr < 2; rr++) {
        int grow = row0 + ty * 2 + rr;
        double A = enormd[grow];
        double m = 1e300; int km = 0;
        #pragma unroll
        for (int q = 0; q < 16; q++) {       // k = q*32+tx ascending in q: first-min kept
            double dq = (A - 2.0 * acc[rr][q]) + cnormd[q * 32 + tx];
            if (dq < m) { m = dq; km = q * 32 + tx; }
        }
        #pragma unroll
        for (int off = 16; off; off >>= 1) { // butterfly within the 32-lane tx group
            double mo = __shfl_xor(m, off);
            int ko = __shfl_xor(km, off);
            if (mo < m || (mo == m && ko < km)) { m = mo; km = ko; }
        }
        if (WANT_PROB) {
            float S = 0.f;
            #pragma unroll
            for (int q = 0; q < 16; q++) {
                double dq = (A - 2.0 * acc[rr][q]) + cnormd[q * 32 + tx];
                S += expf((float)(m - dq));
            }
            #pragma unroll
            for (int off = 16; off; off >>= 1) S += __shfl_xor(S, off);
            if (tx == 0) prob[grow] = expf(-logf(S));
        }
        if (tx == 0) idx[grow] = km;
    }
}

// ---- fuse epilogue: per base pixel pick best scale, gather codes, write all
//      three outputs (out0 here too so encode never needs an LDS transpose).
__launch_bounds__(256)
__global__ void fuse_kernel(const float* __restrict__ feat,
                            const float* __restrict__ prob1,
                            const int* __restrict__ idx1,
                            const int* __restrict__ idx2,
                            const float* __restrict__ cb,   // codebooks[0] base
                            float* __restrict__ out0,
                            float* __restrict__ outZ,
                            float* __restrict__ outS) {
    __shared__ int rsel_s[64], i1_s[64], i2_s[64];
    int tid = threadIdx.x;
    int b = blockIdx.x >> 6, y = blockIdx.x & 63;

    if (tid < 64) {
        int x = tid;
        int r0 = (b * 64 + y) * 64 + x;
        int r1 = 32768 + (b * 32 + (y >> 1)) * 32 + (x >> 1);
        int r2 = 40960 + (b * 16 + (y >> 2)) * 16 + (x >> 2);
        float p0 = prob1[r0], p1 = prob1[r1], p2 = prob1[r2];
        int rsel = r0; float best = p0;      // strict > keeps first-max (jnp.argmax)
        if (p1 > best) { best = p1; rsel = r1; }
        if (p2 > best) { best = p2; rsel = r2; }
        int i1 = idx1[rsel], i2 = idx2[r0];
        rsel_s[x] = rsel; i1_s[x] = i1; i2_s[x] = i2;
        size_t zb = (size_t)b * 8192 + (size_t)y * 64 + x;  // [8][2][64][64]
        outZ[zb] = (float)i1;
        outZ[zb + 4096] = (float)i2;
    }
    __syncthreads();

    int x = tid & 63, cc = tid >> 6;
    int r0 = (b * 64 + y) * 64 + x;
    const float* e0p = feat + (size_t)r0 * 256;
    const float* e1p = feat + (size_t)rsel_s[x] * 256;
    const float* q1p = cb + (size_t)i1_s[x] * 256;
    const float* q2p = cb + (size_t)(512 + i2_s[x]) * 256;
    for (int it = 0; it < 64; it++) {
        int c = it * 4 + cc;
        float e0 = e0p[c], e1 = e1p[c], q1 = q1p[c], q2 = q2p[c];
        size_t o = (((size_t)b * 256 + c) * 64 + y) * 64 + x;  // coalesced over x
        out0[o] = e0;
        float ef = (e1 + e0) * 0.5f;
        float qf = (q1 + q2) * 0.5f;
        outS[o] = ef + (qf - ef);            // reference STE arithmetic order
    }
}

extern "C" void kernel_launch(void* const* d_in, const int* in_sizes, int n_in,
                              void* d_out, int out_size, void* d_ws, size_t ws_size,
                              hipStream_t stream) {
    (void)in_sizes; (void)n_in; (void)out_size; (void)ws_size;
    const float* image     = (const float*)d_in[0];   // [8,3,256,256]
    const float* conv_w    = (const float*)d_in[1];   // [256,3,4,4]
    const float* conv_b    = (const float*)d_in[2];   // [256]
    const float* codebooks = (const float*)d_in[3];   // [4,512,256]

    float*  ws    = (float*)d_ws;
    float*  feat  = ws + FEAT_OFF;
    float*  prob1 = ws + PROB_OFF;
    int*    idx1  = (int*)(ws + IDX1_OFF);
    int*    idx2  = (int*)(ws + IDX2_OFF);
    float*  img1  = ws + IMG1_OFF;
    float*  img2  = ws + IMG2_OFF;
    double* enormd = (double*)(ws + ENORM_OFF);
    double* cnormd = (double*)(ws + CNORM_OFF);

    float* out  = (float*)d_out;
    float* out0 = out;                 // encodes[0] NCHW
    float* outZ = out + 8388608;       // zidx as float, NCHW [8,2,64,64]
    float* outS = out + 8454144;       // ste0 NCHW

    // 1. multi-scale inputs
    ds_kernel<<<1536, 256, 0, stream>>>(image, img1, 128, 128, 0, 2);
    ds_kernel<<<384, 256, 0, stream>>>(image, img2, 64, 64, 1, 4);
    // 2. codebook norms (both books)
    cnorm_kernel<<<1024, 64, 0, stream>>>(codebooks, cnormd);
    // 3. encode each scale (feat rows: 0..32767, 32768..40959, 40960..43007)
    encode_kernel<<<512, 256, 0, stream>>>(image, conv_w, conv_b, feat, enormd, 64, 64, 0);
    encode_kernel<<<256, 256, 0, stream>>>(img1, conv_w, conv_b, feat, enormd, 32, 32, 32768);
    encode_kernel<<<128, 256, 0, stream>>>(img2, conv_w, conv_b, feat, enormd, 16, 16, 40960);
    // 4. match all unique rows vs cb0 (prob+idx), scale0 rows vs cb1 (idx only)
    match_kernel<true><<<2688, 256, 0, stream>>>(feat, enormd, codebooks, cnormd, prob1, idx1);
    match_kernel<false><<<2048, 256, 0, stream>>>(feat, enormd, codebooks + 512 * 256,
                                                  cnormd + 512, nullptr, idx2);
    // 5. fuse + all outputs
    fuse_kernel<<<512, 256, 0, stream>>>(feat, prob1, idx1, idx2, codebooks, out0, outZ, outS);
}

// Round 2
// 764.934 us; speedup vs baseline: 1.5908x; 1.5908x over previous
//
#include <hip/hip_runtime.h>
#include <math.h>

// ---------------------------------------------------------------------------
// VQVAEZMultiScale round 2 — fp64 match kernel rebuilt for throughput.
//   Code-split groups: 8 groups x 32 lanes; each lane owns 2 codes, all 16
//   rows of the block. Each codebook element is read from LDS once per block
//   (float2 + cvt, amortized over 32 fp64 FMAs). acc = 64 VGPR -> 4 waves/SIMD.
//   Distances stay exact fp64 (proven vs np ref in round 1); prob now fp64.
// Workspace layout (float units):
//   feat   [43008][256]        @ 0
//   enormd double[43008]       @ 11010048  (86016 floats)
//   cnormd double[1024]        @ 11096064  (2048 floats)
//   img1   [8][3][128][128]    @ 11098112  (393216)   dead after encode
//   img2   [8][3][64][64]      @ 11491328  (98304)    dead after encode
//   prob1d double[43008]       @ 11098112  (aliases img1)
//   idx1   int[43008]          @ 11184128
//   idx2   int[32768]          @ 11227136  (all aliases end < img2 end)
//   total 11589632 floats = 46.36 MB (<= round-1 footprint)
// Output layout (float, concatenated):
//   out0 encodes[0] NCHW [8][256][64][64]   @ 0
//   out1 zidx NCHW [8][2][64][64] (float)   @ 8388608
//   out2 ste0 NCHW [8][256][64][64]         @ 8454144
// ---------------------------------------------------------------------------

#define FEAT_OFF   0
#define ENORM_OFF  11010048
#define CNORM_OFF  11096064
#define IMG1_OFF   11098112
#define IMG2_OFF   11491328
#define PROBD_OFF  11098112
#define IDX1_OFF   11184128
#define IDX2_OFF   11227136

// ---- bilinear downsample (reference order: H-average first, then W)
__global__ void ds_kernel(const float* __restrict__ img, float* __restrict__ out,
                          int Hout, int Wout, int o, int f) {
    int i = blockIdx.x * blockDim.x + threadIdx.x;
    int total = 8 * 3 * Hout * Wout;
    if (i >= total) return;
    int x = i % Wout;
    int t = i / Wout;
    int y = t % Hout;
    int bc = t / Hout;
    const float* base = img + ((size_t)bc * 256 + (size_t)(y * f + o)) * 256;
    int cx = x * f + o;
    float v00 = base[cx],     v10 = base[256 + cx];
    float v01 = base[cx + 1], v11 = base[256 + cx + 1];
    out[i] = ((v00 + v10) * 0.5f + (v01 + v11) * 0.5f) * 0.5f;
}

// ---- per-code squared norms (fp64), both codebooks
__global__ void cnorm_kernel(const float* __restrict__ cb, double* __restrict__ cnormd) {
    int row = blockIdx.x;                    // 0..1023
    const float* p = cb + (size_t)row * 256;
    int lane = threadIdx.x;                  // 64
    double s = 0.0;
    for (int c = lane; c < 256; c += 64) {
        double v = (double)p[c];
        s = fma(v, v, s);
    }
    #pragma unroll
    for (int off = 32; off; off >>= 1) s += __shfl_down(s, off);
    if (lane == 0) cnormd[row] = s;
}

// ---- stride-4 patchify conv, all 3 scales in one launch.
//      blocks: [0,512) scale0, [512,768) scale1, [768,896) scale2.
__launch_bounds__(256)
__global__ void encode_all(const float* __restrict__ image,
                           const float* __restrict__ img1,
                           const float* __restrict__ img2,
                           const float* __restrict__ w,
                           const float* __restrict__ bias,
                           float* __restrict__ feat,
                           double* __restrict__ enormd) {
    __shared__ float patch[12 * 256];
    __shared__ double wsumd[64][4];
    int bid = blockIdx.x;
    const float* img; int Hout, rowbase, local;
    if (bid < 512)      { img = image; Hout = 64; rowbase = 0;     local = bid; }
    else if (bid < 768) { img = img1;  Hout = 32; rowbase = 32768; local = bid - 512; }
    else                { img = img2;  Hout = 16; rowbase = 40960; local = bid - 768; }
    int Wout = Hout;
    int tid = threadIdx.x;
    int b = local / Hout, y = local % Hout;
    int Himg = Hout * 4, Wimg = Wout * 4;

    const float* ibase = img + (size_t)b * 3 * Himg * Wimg;
    int nload = 12 * Wimg;
    for (int i = tid; i < nload; i += 256) {
        int col = i % Wimg, r = i / Wimg;    // r = ci*4 + kh
        int ci = r >> 2, kh = r & 3;
        patch[r * Wimg + col] = ibase[((size_t)ci * Himg + 4 * y + kh) * Wimg + col];
    }
    float wr[48];
    #pragma unroll
    for (int j = 0; j < 48; j++) wr[j] = w[tid * 48 + j];
    float bv = bias[tid];
    __syncthreads();

    int rb = rowbase + (b * Hout + y) * Wout;
    for (int x = 0; x < Wout; x++) {
        float acc = 0.f;
        #pragma unroll
        for (int ci = 0; ci < 3; ci++)
            #pragma unroll
            for (int kh = 0; kh < 4; kh++) {
                const float* pr = &patch[(ci * 4 + kh) * Wimg + 4 * x];
                #pragma unroll
                for (int kw = 0; kw < 4; kw++)
                    acc = fmaf(pr[kw], wr[ci * 16 + kh * 4 + kw], acc);
            }
        acc += bv;
        feat[(size_t)(rb + x) * 256 + tid] = acc;
        double sq = (double)acc * (double)acc;
        #pragma unroll
        for (int off = 32; off; off >>= 1) sq += __shfl_xor(sq, off);
        if ((tid & 63) == 0) wsumd[x][tid >> 6] = sq;
    }
    __syncthreads();
    if (tid < Wout)
        enormd[rb + tid] = wsumd[tid][0] + wsumd[tid][1] + wsumd[tid][2] + wsumd[tid][3];
}

// ---- fused distance match, both codebooks in one launch.
//      blocks [0,2688): rows vs cb0 (prob+idx1); [2688,4736): scale0 rows vs cb1 (idx2).
//      Per block: 16 rows, 512 codes, K=256. 8 code-groups x 32 lanes;
//      lane owns codes {g*64+tx*2, +1} for all 16 rows. fp64 accumulate.
__launch_bounds__(256, 4)
__global__ void match_all(const float* __restrict__ feat,
                          const double* __restrict__ enormd,
                          const float* __restrict__ codebooks,
                          const double* __restrict__ cnormd_all,
                          double* __restrict__ prob,
                          int* __restrict__ idx1,
                          int* __restrict__ idx2) {
    __shared__ float  ctf[8][512];
    __shared__ double etd[8][16];
    __shared__ double red_m[4][16];
    __shared__ int    red_k[4][16];
    __shared__ double red_s[4][16];
    __shared__ double gm[16];

    int bid = blockIdx.x;
    bool want_prob = bid < 2688;
    int row0; const float* cb; const double* cnormd; int* idx;
    if (want_prob) { row0 = bid * 16;          cb = codebooks;             cnormd = cnormd_all;       idx = idx1; }
    else           { row0 = (bid - 2688) * 16; cb = codebooks + 512 * 256; cnormd = cnormd_all + 512; idx = idx2; }

    int tid = threadIdx.x;
    int g  = tid >> 5;            // code group
    int tx = tid & 31;
    int k0 = g * 64 + tx * 2;     // lane's first code

    double acc0[16], acc1[16];
    #pragma unroll
    for (int r = 0; r < 16; r++) { acc0[r] = 0.0; acc1[r] = 0.0; }

    for (int c0 = 0; c0 < 256; c0 += 8) {
        // stage codebook tile [8 kc][512 k] as float (each elem read once below)
        #pragma unroll
        for (int i = 0; i < 4; i++) {
            int fid = i * 256 + tid;              // 0..1023
            int k = fid >> 1, c4 = (fid & 1) * 4;
            const float4 v = *(const float4*)(cb + (size_t)k * 256 + c0 + c4);
            ctf[c4 + 0][k] = v.x; ctf[c4 + 1][k] = v.y;
            ctf[c4 + 2][k] = v.z; ctf[c4 + 3][k] = v.w;
        }
        // stage feature tile [8 kc][16 r] as double
        if (tid < 128) {
            int r = tid >> 3, kc = tid & 7;
            etd[kc][r] = (double)feat[(size_t)(row0 + r) * 256 + c0 + kc];
        }
        __syncthreads();
        #pragma unroll
        for (int kc = 0; kc < 8; kc++) {
            float2 cf = *(const float2*)&ctf[kc][k0];
            double cv0 = (double)cf.x, cv1 = (double)cf.y;
            const double2* ep = (const double2*)&etd[kc][0];
            #pragma unroll
            for (int h = 0; h < 8; h++) {
                double2 e2 = ep[h];               // uniform b128 broadcast
                acc0[2 * h]     = fma(e2.x, cv0, acc0[2 * h]);
                acc1[2 * h]     = fma(e2.x, cv1, acc1[2 * h]);
                acc0[2 * h + 1] = fma(e2.y, cv0, acc0[2 * h + 1]);
                acc1[2 * h + 1] = fma(e2.y, cv1, acc1[2 * h + 1]);
            }
        }
        __syncthreads();
    }

    double cn0 = cnormd[k0], cn1 = cnormd[k0 + 1];
    int wave = tid >> 6, lane = tid & 63;

    // phase 1: per-wave lexicographic (d, k) min for each row
    #pragma unroll
    for (int r = 0; r < 16; r++) {
        double A = enormd[row0 + r];
        double d0 = (A - 2.0 * acc0[r]) + cn0;
        double d1 = (A - 2.0 * acc1[r]) + cn1;
        double m = d0; int km = k0;
        if (d1 < m) { m = d1; km = k0 + 1; }
        #pragma unroll
        for (int off = 32; off; off >>= 1) {
            double mo = __shfl_xor(m, off);
            int ko = __shfl_xor(km, off);
            if (mo < m || (mo == m && ko < km)) { m = mo; km = ko; }
        }
        if (lane == 0) { red_m[wave][r] = m; red_k[wave][r] = km; }
    }
    __syncthreads();
    // phase 2: combine the 4 wave partials (order-independent lexicographic min)
    if (tid < 16) {
        double m = red_m[0][tid]; int km = red_k[0][tid];
        #pragma unroll
        for (int w = 1; w < 4; w++) {
            double mo = red_m[w][tid]; int ko = red_k[w][tid];
            if (mo < m || (mo == m && ko < km)) { m = mo; km = ko; }
        }
        gm[tid] = m;
        idx[row0 + tid] = km;
    }
    if (want_prob) {
        __syncthreads();
        // phase 3: S = sum exp(m - d) in fp64
        #pragma unroll
        for (int r = 0; r < 16; r++) {
            double A = enormd[row0 + r];
            double d0 = (A - 2.0 * acc0[r]) + cn0;
            double d1 = (A - 2.0 * acc1[r]) + cn1;
            double m = gm[r];
            double S = exp(m - d0) + exp(m - d1);
            #pragma unroll
            for (int off = 32; off; off >>= 1) S += __shfl_xor(S, off);
            if (lane == 0) red_s[wave][r] = S;
        }
        __syncthreads();
        if (tid < 16) {
            double S = ((red_s[0][tid] + red_s[1][tid]) + red_s[2][tid]) + red_s[3][tid];
            prob[row0 + tid] = 1.0 / S;   // == exp(max - logsumexp) to ~1e-16
        }
    }
}

// ---- fuse epilogue: per base pixel pick best scale, gather codes, write outputs
__launch_bounds__(256)
__global__ void fuse_kernel(const float* __restrict__ feat,
                            const double* __restrict__ prob1,
                            const int* __restrict__ idx1,
                            const int* __restrict__ idx2,
                            const float* __restrict__ cb,
                            float* __restrict__ out0,
                            float* __restrict__ outZ,
                            float* __restrict__ outS) {
    __shared__ int rsel_s[64], i1_s[64], i2_s[64];
    int tid = threadIdx.x;
    int b = blockIdx.x >> 6, y = blockIdx.x & 63;

    if (tid < 64) {
        int x = tid;
        int r0 = (b * 64 + y) * 64 + x;
        int r1 = 32768 + (b * 32 + (y >> 1)) * 32 + (x >> 1);
        int r2 = 40960 + (b * 16 + (y >> 2)) * 16 + (x >> 2);
        double p0 = prob1[r0], p1 = prob1[r1], p2 = prob1[r2];
        int rsel = r0; double best = p0;     // strict > keeps first-max (jnp.argmax)
        if (p1 > best) { best = p1; rsel = r1; }
        if (p2 > best) { best = p2; rsel = r2; }
        int i1 = idx1[rsel], i2 = idx2[r0];
        rsel_s[x] = rsel; i1_s[x] = i1; i2_s[x] = i2;
        size_t zb = (size_t)b * 8192 + (size_t)y * 64 + x;
        outZ[zb] = (float)i1;
        outZ[zb + 4096] = (float)i2;
    }
    __syncthreads();

    int x = tid & 63, cc = tid >> 6;
    int r0 = (b * 64 + y) * 64 + x;
    const float* e0p = feat + (size_t)r0 * 256;
    const float* e1p = feat + (size_t)rsel_s[x] * 256;
    const float* q1p = cb + (size_t)i1_s[x] * 256;
    const float* q2p = cb + (size_t)(512 + i2_s[x]) * 256;
    for (int it = 0; it < 64; it++) {
        int c = it * 4 + cc;
        float e0 = e0p[c], e1 = e1p[c], q1 = q1p[c], q2 = q2p[c];
        size_t o = (((size_t)b * 256 + c) * 64 + y) * 64 + x;
        out0[o] = e0;
        float ef = (e1 + e0) * 0.5f;
        float qf = (q1 + q2) * 0.5f;
        outS[o] = ef + (qf - ef);
    }
}

extern "C" void kernel_launch(void* const* d_in, const int* in_sizes, int n_in,
                              void* d_out, int out_size, void* d_ws, size_t ws_size,
                              hipStream_t stream) {
    (void)in_sizes; (void)n_in; (void)out_size; (void)ws_size;
    const float* image     = (const float*)d_in[0];   // [8,3,256,256]
    const float* conv_w    = (const float*)d_in[1];   // [256,3,4,4]
    const float* conv_b    = (const float*)d_in[2];   // [256]
    const float* codebooks = (const float*)d_in[3];   // [4,512,256]

    float*  ws     = (float*)d_ws;
    float*  feat   = ws + FEAT_OFF;
    double* enormd = (double*)(ws + ENORM_OFF);
    double* cnormd = (double*)(ws + CNORM_OFF);
    float*  img1   = ws + IMG1_OFF;
    float*  img2   = ws + IMG2_OFF;
    double* prob1d = (double*)(ws + PROBD_OFF);       // aliases img1 (dead by then)
    int*    idx1   = (int*)(ws + IDX1_OFF);
    int*    idx2   = (int*)(ws + IDX2_OFF);

    float* out  = (float*)d_out;
    float* out0 = out;
    float* outZ = out + 8388608;
    float* outS = out + 8454144;

    ds_kernel<<<1536, 256, 0, stream>>>(image, img1, 128, 128, 0, 2);
    ds_kernel<<<384, 256, 0, stream>>>(image, img2, 64, 64, 1, 4);
    cnorm_kernel<<<1024, 64, 0, stream>>>(codebooks, cnormd);
    encode_all<<<896, 256, 0, stream>>>(image, img1, img2, conv_w, conv_b, feat, enormd);
    match_all<<<4736, 256, 0, stream>>>(feat, enormd, codebooks, cnormd, prob1d, idx1, idx2);
    fuse_kernel<<<512, 256, 0, stream>>>(feat, prob1d, idx1, idx2, codebooks, out0, outZ, outS);
}